// Round 7
// baseline (354.107 us; speedup 1.0000x reference)
//
#include <hip/hip_runtime.h>
#include <hip/hip_bf16.h>
#include <hip/hip_cooperative_groups.h>

namespace cg = cooperative_groups;

// ---------------------------------------------------------------------------
// InferCellV2 R7: single cooperative persistent kernel (grid 256 = 1 block/CU,
// 512 thr) fusing pre-pass + 3 conv stages with grid.sync() between phases
// (kills ~8us/dispatch gaps). Inner loop: half-tap register double-buffer —
// prefetch next 8 ds_read_b128 before current 16 MFMAs so LDS pipe and MFMA
// pipe overlap instead of phase-alternating (R6 lesson).
// Layouts (R3-verified conflict-free): padded NHWC bf16 [B][34][34][64] with
// 16B chunk cb of pixel p at p*128+((cb^(p&7))*16); weights wt[l][tap][o][i]
// with chunk i>>3 of row o at slot (i>>3)^(o&7). LDS 152064 B dynamic.
// Fallback: if cooperative launch fails (capture), same phases run as 4
// classic dispatches (deterministic branch).
// ---------------------------------------------------------------------------

typedef __bf16 bf16x8 __attribute__((ext_vector_type(8)));
typedef float floatx4 __attribute__((ext_vector_type(4)));
typedef unsigned int uint32;

#define PADW 34
#define PIMG (PADW * PADW)
#define ROWB (PADW * 64 * 2)        // 4352 B per padded NHWC row
#define A_LDS (18 * ROWB)           // 78336 (16 out rows + 2 halo)
#define A_CHUNKS (A_LDS / 16)       // 4896 = 9*512 + 288
#define TAPB (64 * 64 * 2)          // 8192 B per weight tap
#define B_LDS (9 * TAPB)            // 73728
#define SMEM_BYTES (A_LDS + B_LDS)  // 152064 <= 160KB/CU

__device__ __forceinline__ void gld16(const char* g, char* l) {
    __builtin_amdgcn_global_load_lds(
        (const __attribute__((address_space(1))) uint32*)g,
        (__attribute__((address_space(3))) uint32*)l, 16, 0, 0);
}

// ---------------- phase P: weights fold + halo zero + relu/pad/swizzle ------
__device__ __forceinline__ void pre_phase(
    int blk, int tid, char* smem,
    const float* __restrict__ in, const float* __restrict__ a1,
    const float* __restrict__ a2, const float* __restrict__ W,
    __hip_bfloat16* __restrict__ wt, __hip_bfloat16* __restrict__ r0,
    __hip_bfloat16* __restrict__ r1, __hip_bfloat16* __restrict__ r2) {
    // (a) fold rank-1 channel scale into weights, transpose+swizzle
    for (int t = tid; t < 864; t += 512) {       // 256 blk * 864 = 221184
        int idx = blk * 864 + t;
        int i = idx & 63, o = (idx >> 6) & 63;
        int rest = idx >> 12;
        int tt = rest % 9, l = rest / 9;
        int ji = i >> 3, jo = o >> 3;
        float ain = 0.f, aout = 0.f;
#pragma unroll
        for (int j = 0; j < 8; ++j) {
            ain  += (j >= ji) ? a1[j] : 0.f;
            aout += (j >= jo) ? a2[j] : 0.f;
        }
        float v = W[(size_t)((l * 64 + o) * 64 + i) * 9 + tt] * ain * aout;
        size_t e = (size_t)(l * 9 + tt) * 4096 + o * 64 +
                   ((((i >> 3) ^ (o & 7)) << 3) + (i & 7));
        wt[e] = __float2bfloat16(v);
    }
    // (b) zero halo ring of all three activation buffers (blocks 0..127)
    if (blk < 128) {
        __hip_bfloat16* bufs[3] = {r0, r1, r2};
#pragma unroll
        for (int f = 0; f < 3; ++f) {
            uint32* buf = (uint32*)(bufs[f] + (size_t)blk * PIMG * 64);
            for (int idx = tid; idx < 132 * 32; idx += 512) {
                int slot = idx >> 5, u = idx & 31;
                int yy, xx;
                if (slot < 34)      { yy = 0;  xx = slot; }
                else if (slot < 68) { yy = 33; xx = slot - 34; }
                else { int s2 = slot - 68; yy = 1 + (s2 >> 1); xx = (s2 & 1) * 33; }
                buf[(size_t)(yy * PADW + xx) * 32 + u] = 0u;
            }
        }
    }
    // (c) relu(x) NCHW fp32 -> padded swizzled NHWC bf16 (16 rows per block)
    float (*tile)[65] = (float (*)[65])smem;
    for (int j = 0; j < 16; ++j) {
        int rb = (blk << 4) + j;                 // 0..4095 = (b,y)
        int bb = rb >> 5, y = rb & 31;
        __syncthreads();
        int x = tid & 31, c0 = tid >> 5;         // c0 0..15
        const float* ip = in + ((size_t)bb * 2048 + y) * 32 + x;
#pragma unroll
        for (int cc = 0; cc < 4; ++cc) {
            int c = (cc << 4) + c0;
            tile[x][c] = fmaxf(ip[(size_t)c * 1024], 0.f);
        }
        __syncthreads();
        int o = tid & 63, xg = tid >> 6;         // xg 0..7
        int p0 = (bb * PADW + y + 1) * PADW + 1;
#pragma unroll
        for (int xx = 0; xx < 4; ++xx) {
            int xq = (xx << 3) + xg;
            int p = p0 + xq;
            size_t e = (size_t)p * 64 + ((((o >> 3) ^ (p & 7)) << 3) + (o & 7));
            r0[e] = __float2bfloat16(tile[xq][o]);
        }
    }
}

// ---------------- conv phase: pipelined, barrier-free within a source -------
// Block: image b, 16-row strip y0. Wave wv: rows y0+2wv, +1 (64 px x 64 oc).
template <int NSRC, bool FINAL>
__device__ __forceinline__ void conv_phase(
    char* smem, const char* s0, const char* s1, const char* s2,
    const char* wtc, void* dstv, int l0,
    int b, int y0, int wv, int quad, int l15, int tid) {
    char* smemB = smem + A_LDS;
    const char* srcs[3] = {s0, s1, s2};
    const char* gW = wtc + (size_t)l0 * 9 * (size_t)TAPB;

    auto stage_A = [&](int s) {      // 18 padded rows, linear 16B DMA copy
        const char* gA = srcs[s] + (size_t)(b * PADW + y0) * PADW * 128;
#pragma unroll
        for (int it = 0; it < 10; ++it) {
            int c = it * 512 + tid;
            if (it < 9 || tid < A_CHUNKS - 9 * 512)
                gld16(gA + (size_t)c * 16, smem + (it * 512 + wv * 64) * 16);
        }
    };
    auto stage_B = [&](int s) {      // 9 taps of src s, linear 16B DMA copy
        const char* gB = gW + (size_t)s * 9 * TAPB;
#pragma unroll
        for (int it = 0; it < 9; ++it) {
            int c = it * 512 + tid;
            gld16(gB + (size_t)c * 16, smemB + (it * 512 + wv * 64) * 16);
        }
    };

    floatx4 acc[4][4];
#pragma unroll
    for (int m = 0; m < 4; ++m)
#pragma unroll
        for (int n = 0; n < 4; ++n) acc[m][n] = (floatx4){0.f, 0.f, 0.f, 0.f};

    stage_A(0);
    stage_B(0);
    __syncthreads();                 // src0 operands resident

#pragma unroll 1
    for (int s = 0; s < NSRC; ++s) {
        bf16x8 Af[2][4], Bf[2][4];   // half-tap double buffer (h = tl*2+q)
        auto load_half = [&](int h, int set) {
            int tl = h >> 1, q = h & 1, ky = tl / 3, kx = tl % 3;
#pragma unroll
            for (int m = 0; m < 4; ++m) {
                int arow = 2 * wv + (m >> 1) + ky;      // LDS row 0..17
                int apx  = ((m & 1) << 4) + l15 + kx;   // 0..33
                int ph   = (2 * (b * PADW + y0 + arow) + apx) & 7;
                int slot = ((q << 2) + quad) ^ ph;
                Af[set][m] = *(const bf16x8*)(smem + arow * ROWB +
                                              apx * 128 + slot * 16);
            }
#pragma unroll
            for (int n = 0; n < 4; ++n) {
                int o = (n << 4) + l15;
                int slot = ((q << 2) + quad) ^ (l15 & 7);
                Bf[set][n] = *(const bf16x8*)(smemB + tl * TAPB +
                                              o * 128 + slot * 16);
            }
        };
        load_half(0, 0);
#pragma unroll
        for (int h = 0; h < 18; ++h) {
            if (h + 1 < 18) load_half(h + 1, (h + 1) & 1);  // prefetch
            const int set = h & 1;
#pragma unroll
            for (int m = 0; m < 4; ++m)
#pragma unroll
                for (int n = 0; n < 4; ++n)
                    acc[m][n] = __builtin_amdgcn_mfma_f32_16x16x32_bf16(
                        Af[set][m], Bf[set][n], acc[m][n], 0, 0, 0);
        }
        if (s + 1 < NSRC) {          // source switch: the only barriers
            __syncthreads();
            stage_A(s + 1);
            stage_B(s + 1);
            __syncthreads();
        }
    }

    // Epilogue. M(pixel) = quad*4+r (+16 for odd m-tile), N(oc) = n*16+l15.
    if (FINAL) {
        float* out = (float*)dstv;   // fp32 NCHW [128][64][32][32]
#pragma unroll
        for (int m = 0; m < 4; ++m) {
            int row = y0 + 2 * wv + (m >> 1);
#pragma unroll
            for (int n = 0; n < 4; ++n) {
                int o = (n << 4) + l15;
                *(floatx4*)(out + (((size_t)b * 64 + o) * 32 + row) * 32 +
                            ((m & 1) << 4) + (quad << 2)) = acc[m][n];
            }
        }
    } else {
        __hip_bfloat16* out = (__hip_bfloat16*)dstv;  // relu -> swizzled NHWC
#pragma unroll
        for (int m = 0; m < 4; ++m) {
            int row = y0 + 2 * wv + (m >> 1);
#pragma unroll
            for (int n = 0; n < 4; ++n) {
                int o = (n << 4) + l15;
#pragma unroll
                for (int r = 0; r < 4; ++r) {
                    int x = ((m & 1) << 4) + (quad << 2) + r;
                    int p = (b * PADW + row + 1) * PADW + x + 1;
                    float v = fmaxf(acc[m][n][r], 0.f);
                    size_t e = (size_t)p * 64 +
                               ((((o >> 3) ^ (p & 7)) << 3) + (o & 7));
                    out[e] = __float2bfloat16(v);
                }
            }
        }
    }
}

// ---------------- fused cooperative kernel ----------------------------------
__global__ __launch_bounds__(512, 2) void fused_kernel(
    const float* __restrict__ in, const float* __restrict__ a1,
    const float* __restrict__ a2, const float* __restrict__ W,
    __hip_bfloat16* wt, __hip_bfloat16* r0, __hip_bfloat16* r1,
    __hip_bfloat16* r2, float* out) {
    extern __shared__ char smem[];
    int blk = blockIdx.x, tid = threadIdx.x;
    pre_phase(blk, tid, smem, in, a1, a2, W, wt, r0, r1, r2);
    cg::this_grid().sync();
    int lane = tid & 63;
    int wv = tid >> 6, quad = lane >> 4, l15 = lane & 15;
    int b = blk >> 1, y0 = (blk & 1) << 4;
    conv_phase<1, false>(smem, (const char*)r0, (const char*)r1,
                         (const char*)r2, (const char*)wt, (void*)r1, 0,
                         b, y0, wv, quad, l15, tid);
    cg::this_grid().sync();
    conv_phase<2, false>(smem, (const char*)r0, (const char*)r1,
                         (const char*)r2, (const char*)wt, (void*)r2, 1,
                         b, y0, wv, quad, l15, tid);
    cg::this_grid().sync();
    conv_phase<3, true>(smem, (const char*)r0, (const char*)r1,
                        (const char*)r2, (const char*)wt, (void*)out, 3,
                        b, y0, wv, quad, l15, tid);
}

// ---------------- fallback standalone kernels (if coop launch fails) --------
__global__ __launch_bounds__(512) void pre_kernel_sa(
    const float* __restrict__ in, const float* __restrict__ a1,
    const float* __restrict__ a2, const float* __restrict__ W,
    __hip_bfloat16* wt, __hip_bfloat16* r0, __hip_bfloat16* r1,
    __hip_bfloat16* r2) {
    extern __shared__ char smem[];
    pre_phase(blockIdx.x, threadIdx.x, smem, in, a1, a2, W, wt, r0, r1, r2);
}

template <int NSRC, bool FINAL>
__global__ __launch_bounds__(512, 2) void conv_sa(
    const __hip_bfloat16* s0, const __hip_bfloat16* s1,
    const __hip_bfloat16* s2, const __hip_bfloat16* wt, void* dstv, int l0) {
    extern __shared__ char smem[];
    int blk = blockIdx.x, tid = threadIdx.x;
    int lane = tid & 63;
    int wv = tid >> 6, quad = lane >> 4, l15 = lane & 15;
    int b = blk >> 1, y0 = (blk & 1) << 4;
    conv_phase<NSRC, FINAL>(smem, (const char*)s0, (const char*)s1,
                            (const char*)s2, (const char*)wt, dstv, l0,
                            b, y0, wv, quad, l15, tid);
}

// ---------------------------------------------------------------------------
extern "C" void kernel_launch(void* const* d_in, const int* in_sizes, int n_in,
                              void* d_out, int out_size, void* d_ws,
                              size_t ws_size, hipStream_t stream) {
    const float* inputs  = (const float*)d_in[0];
    const float* alphas1 = (const float*)d_in[1];
    const float* alphas2 = (const float*)d_in[2];
    const float* W       = (const float*)d_in[3];
    char* ws = (char*)d_ws;

    __hip_bfloat16* wt = (__hip_bfloat16*)(ws);                     // 442 KB
    __hip_bfloat16* r0 = (__hip_bfloat16*)(ws + ((size_t)1 << 20)); // 18.9 MB
    __hip_bfloat16* r1 = (__hip_bfloat16*)(ws + ((size_t)20 << 20));
    __hip_bfloat16* r2 = (__hip_bfloat16*)(ws + ((size_t)40 << 20));
    float* out = (float*)d_out;

    // Opt-in to >64KB dynamic LDS (host-side attr, idempotent).
    (void)hipFuncSetAttribute((const void*)fused_kernel,
                              hipFuncAttributeMaxDynamicSharedMemorySize,
                              SMEM_BYTES);
    (void)hipFuncSetAttribute((const void*)pre_kernel_sa,
                              hipFuncAttributeMaxDynamicSharedMemorySize,
                              SMEM_BYTES);
    (void)hipFuncSetAttribute((const void*)conv_sa<1, false>,
                              hipFuncAttributeMaxDynamicSharedMemorySize,
                              SMEM_BYTES);
    (void)hipFuncSetAttribute((const void*)conv_sa<2, false>,
                              hipFuncAttributeMaxDynamicSharedMemorySize,
                              SMEM_BYTES);
    (void)hipFuncSetAttribute((const void*)conv_sa<3, true>,
                              hipFuncAttributeMaxDynamicSharedMemorySize,
                              SMEM_BYTES);

    void* args[9] = {(void*)&inputs, (void*)&alphas1, (void*)&alphas2,
                     (void*)&W, (void*)&wt, (void*)&r0, (void*)&r1,
                     (void*)&r2, (void*)&out};
    hipError_t e = hipLaunchCooperativeKernel((const void*)fused_kernel,
                                              dim3(256), dim3(512), args,
                                              (unsigned)SMEM_BYTES, stream);
    if (e != hipSuccess) {
        (void)hipGetLastError();     // clear sticky error; use classic path
        pre_kernel_sa<<<256, 512, SMEM_BYTES, stream>>>(inputs, alphas1,
                                                        alphas2, W, wt, r0,
                                                        r1, r2);
        conv_sa<1, false><<<256, 512, SMEM_BYTES, stream>>>(r0, r1, r2, wt,
                                                            (void*)r1, 0);
        conv_sa<2, false><<<256, 512, SMEM_BYTES, stream>>>(r0, r1, r2, wt,
                                                            (void*)r2, 1);
        conv_sa<3, true ><<<256, 512, SMEM_BYTES, stream>>>(r0, r1, r2, wt,
                                                            (void*)out, 3);
    }
}